// Round 1
// baseline (201.838 us; speedup 1.0000x reference)
//
#include <hip/hip_runtime.h>

// AttentionBlock: B=8, C=128, H=W=128, GROUPS=8, HEADS=8, HEAD_DIM=16
// R2: kill the GEMM1 recompute in k_attn_out by spilling h1 (bf16, [b][p][c]) to
//     global in k_gemm1_scores. A-operands (w_in*s, w_eff) prebaked to bf16 in
//     global by k_prep / k_softmax_weff and loaded as MFMA fragments directly.
//     K2 LDS 70->35 KiB (4 blocks/CU); K4 LDS 70 KiB -> 512 B (VGPR-limited occ).

#define NPOS 16384          // 128*128 spatial
#define PITCH 136           // LDS row pitch in ushorts

typedef short short8 __attribute__((ext_vector_type(8)));   // 8 bf16 (4 VGPRs)
typedef float f32x4 __attribute__((ext_vector_type(4)));

__device__ __forceinline__ unsigned short f2bf(float f) {
    union { float f; unsigned u; } v; v.f = f;
    unsigned r = (v.u + 0x7fffu + ((v.u >> 16) & 1u)) >> 16;
    return (unsigned short)r;
}

// ---------------- K1: per-(b,g) sum / sumsq ----------------
__global__ __launch_bounds__(256) void k_stats(const float* __restrict__ x,
                                               float* __restrict__ stats) {
    const float4* p = (const float4*)(x + (size_t)blockIdx.x * 16384);
    int t = threadIdx.x;
    float s1 = 0.f, s2 = 0.f;
#pragma unroll
    for (int j = 0; j < 16; ++j) {
        float4 v = p[t + j * 256];
        s1 += v.x + v.y + v.z + v.w;
        s2 += v.x * v.x + v.y * v.y + v.z * v.z + v.w * v.w;
    }
    for (int off = 32; off; off >>= 1) {
        s1 += __shfl_down(s1, off);
        s2 += __shfl_down(s2, off);
    }
    __shared__ float r1[4], r2[4];
    int wv = t >> 6;
    if ((t & 63) == 0) { r1[wv] = s1; r2[wv] = s2; }
    __syncthreads();
    if (t == 0) {
        s1 = r1[0] + r1[1] + r1[2] + r1[3];
        s2 = r2[0] + r2[1] + r2[2] + r2[3];
        int bg = blockIdx.x >> 4;
        atomicAdd(&stats[bg * 2 + 0], s1);
        atomicAdd(&stats[bg * 2 + 1], s2);
    }
}

// ---------------- K1b: fold GN into conv_in; bake A = bf16(w_in*s) per batch ----
__global__ __launch_bounds__(128) void k_prep(const float* __restrict__ stats,
                                              const float* __restrict__ gn_w,
                                              const float* __restrict__ gn_b,
                                              const float* __restrict__ w_in,
                                              const float* __restrict__ b_in,
                                              float* __restrict__ vA,
                                              unsigned short* __restrict__ Asb) {
    int b = blockIdx.x, c = threadIdx.x;
    int g = c >> 4;
    float s1 = stats[(b * 8 + g) * 2 + 0];
    float s2 = stats[(b * 8 + g) * 2 + 1];
    const float invN = 1.0f / 262144.0f;   // 16 ch * 16384 pos
    float mean = s1 * invN;
    float var = s2 * invN - mean * mean;
    float rstd = rsqrtf(var + 1e-5f);
    float s = gn_w[c] * rstd;
    float tt = gn_b[c] - mean * s;
    __shared__ float tl[128], sl[128];
    tl[c] = tt; sl[c] = s;
    __syncthreads();
    float v = b_in[c];
    const float* wr = w_in + c * 128;
    unsigned short* ar = Asb + b * 16384 + c * 128;
#pragma unroll 8
    for (int k = 0; k < 128; k += 4) {
        float4 w = *(const float4*)&wr[k];
        v += w.x * tl[k] + w.y * tl[k + 1] + w.z * tl[k + 2] + w.w * tl[k + 3];
        ushort4 o;
        o.x = f2bf(w.x * sl[k]);     o.y = f2bf(w.y * sl[k + 1]);
        o.z = f2bf(w.z * sl[k + 2]); o.w = f2bf(w.w * sl[k + 3]);
        *(ushort4*)&ar[k] = o;
    }
    vA[b * 128 + c] = v;
}

// ---------------- K2: h1 = A@x + v (-> global h1t bf16) ; partial S = H H^T ----
__global__ __launch_bounds__(256, 4) void k_gemm1_scores(const float* __restrict__ x,
                                                         const unsigned short* __restrict__ Asb,
                                                         const float* __restrict__ vA,
                                                         unsigned short* __restrict__ h1t,
                                                         float* __restrict__ Sg) {
    __shared__ unsigned short Xt[128 * PITCH];
    __shared__ float v_s[128];

    const int t = threadIdx.x;
    const int lane = t & 63, wv = t >> 6;
    const int q = lane >> 4, i16 = lane & 15;
    const int b = blockIdx.x >> 7;
    const int p0 = (blockIdx.x & 127) << 7;

    if (t < 128) v_s[t] = vA[b * 128 + t];

    // stage Xt[p][k] = bf16(x[k][p0+p])  (transpose)
    const float* xb = x + (size_t)b * (128 * NPOS) + p0;
#pragma unroll
    for (int i = 0; i < 16; ++i) {
        int p = ((i & 1) << 6) + lane;
        int kq = (wv << 3) + (i >> 1);
        const float* col = xb + (size_t)(kq * 4) * NPOS + p;
        float a0 = col[0];
        float a1 = col[NPOS];
        float a2 = col[2 * NPOS];
        float a3 = col[3 * NPOS];
        ushort4 o; o.x = f2bf(a0); o.y = f2bf(a1); o.z = f2bf(a2); o.w = f2bf(a3);
        *(ushort4*)&Xt[p * PITCH + kq * 4] = o;
    }
    __syncthreads();

    f32x4 acc[2][8];
#pragma unroll
    for (int a = 0; a < 2; ++a)
#pragma unroll
        for (int pt = 0; pt < 8; ++pt) acc[a][pt] = (f32x4){0.f, 0.f, 0.f, 0.f};

    const unsigned short* Ab = Asb + b * 16384;
#pragma unroll
    for (int ks = 0; ks < 4; ++ks) {
        short8 a0 = *(const short8*)&Ab[(wv * 32 + i16) * 128 + ks * 32 + q * 8];
        short8 a1 = *(const short8*)&Ab[(wv * 32 + 16 + i16) * 128 + ks * 32 + q * 8];
#pragma unroll
        for (int pt = 0; pt < 8; ++pt) {
            short8 bb = *(const short8*)&Xt[(pt * 16 + i16) * PITCH + ks * 32 + q * 8];
            acc[0][pt] = __builtin_amdgcn_mfma_f32_16x16x32_bf16(a0, bb, acc[0][pt], 0, 0, 0);
            acc[1][pt] = __builtin_amdgcn_mfma_f32_16x16x32_bf16(a1, bb, acc[1][pt], 0, 0, 0);
        }
    }
    __syncthreads();            // Xt dead -> reuse as Hs[c][p]

    unsigned short* Hs = Xt;
    unsigned short* hb = h1t + ((size_t)b * NPOS + p0) * 128;
#pragma unroll
    for (int a = 0; a < 2; ++a) {
        int cb = wv * 32 + a * 16 + q * 4;
#pragma unroll
        for (int pt = 0; pt < 8; ++pt) {
            int p = pt * 16 + i16;
            ushort4 o;
            o.x = f2bf(acc[a][pt][0] + v_s[cb + 0]);
            o.y = f2bf(acc[a][pt][1] + v_s[cb + 1]);
            o.z = f2bf(acc[a][pt][2] + v_s[cb + 2]);
            o.w = f2bf(acc[a][pt][3] + v_s[cb + 3]);
            Hs[(cb + 0) * PITCH + p] = o.x;
            Hs[(cb + 1) * PITCH + p] = o.y;
            Hs[(cb + 2) * PITCH + p] = o.z;
            Hs[(cb + 3) * PITCH + p] = o.w;
            *(ushort4*)&hb[(size_t)p * 128 + cb] = o;   // h1t[b][p][c] bf16
        }
    }
    __syncthreads();

    // S partial: wave wv handles heads 2wv, 2wv+1 ; A==B frag (H H^T)
#pragma unroll
    for (int hh = 0; hh < 2; ++hh) {
        int h = wv * 2 + hh;
        f32x4 sacc = (f32x4){0.f, 0.f, 0.f, 0.f};
#pragma unroll
        for (int ks = 0; ks < 4; ++ks) {
            short8 f = *(const short8*)&Hs[(h * 16 + i16) * PITCH + ks * 32 + q * 8];
            sacc = __builtin_amdgcn_mfma_f32_16x16x32_bf16(f, f, sacc, 0, 0, 0);
        }
        float* sg = Sg + (b * 8 + h) * 256;
#pragma unroll
        for (int r = 0; r < 4; ++r)
            atomicAdd(&sg[(q * 4 + r) * 16 + i16], sacc[r]);
    }
}

// ---------------- K3: softmax + w_eff[b] = bf16(w_out @ blockdiag(W)) ----------
__global__ __launch_bounds__(256) void k_softmax_weff(const float* __restrict__ Sg,
                                                      const float* __restrict__ w_out,
                                                      unsigned short* __restrict__ weffb) {
    int b = blockIdx.x >> 3;      // 8 chunks per batch for parallelism
    int ch = blockIdx.x & 7;
    int t = threadIdx.x;
    __shared__ float W[2048];
    if (t < 128) {
        const float* row = Sg + b * 2048 + t * 16;
        float v[16];
        float m = -1e30f;
#pragma unroll
        for (int j = 0; j < 16; ++j) { v[j] = row[j] * 0.25f; m = fmaxf(m, v[j]); }
        float sum = 0.f;
#pragma unroll
        for (int j = 0; j < 16; ++j) { v[j] = __expf(v[j] - m); sum += v[j]; }
        float inv = 1.0f / sum;
#pragma unroll
        for (int j = 0; j < 16; ++j) W[t * 16 + j] = v[j] * inv;
    }
    __syncthreads();
    unsigned short* wo = weffb + b * 16384 + ch * 2048;   // 16 c-rows per block
#pragma unroll
    for (int n = 0; n < 8; ++n) {
        int idx = t + n * 256;
        int c = idx >> 7, k = idx & 127;
        int h = k >> 4, j = k & 15;
        const float* wr = w_out + (ch * 16 + c) * 128 + h * 16;
        const float* Wr = W + h * 256 + j;
        float a = 0.f;
#pragma unroll
        for (int i = 0; i < 16; ++i) a += wr[i] * Wr[i * 16];
        wo[idx] = f2bf(a);
    }
}

// ---------------- K4: out = x + b_out + w_eff @ h1 (fragments straight from global)
__global__ __launch_bounds__(256, 4) void k_attn_out(const float* __restrict__ x,
                                                     const unsigned short* __restrict__ weffb,
                                                     const unsigned short* __restrict__ h1t,
                                                     const float* __restrict__ b_out,
                                                     float* __restrict__ out) {
    __shared__ float bo_s[128];
    const int t = threadIdx.x;
    const int lane = t & 63, wv = t >> 6;
    const int q = lane >> 4, i16 = lane & 15;
    const int b = blockIdx.x >> 7;
    const int p0 = (blockIdx.x & 127) << 7;

    if (t < 128) bo_s[t] = b_out[t];
    __syncthreads();

    f32x4 acc[2][8];
#pragma unroll
    for (int a = 0; a < 2; ++a)
#pragma unroll
        for (int pt = 0; pt < 8; ++pt) acc[a][pt] = (f32x4){0.f, 0.f, 0.f, 0.f};

    const unsigned short* Wb = weffb + b * 16384;
    const unsigned short* Hb = h1t + ((size_t)b * NPOS + p0) * 128;
#pragma unroll
    for (int ks = 0; ks < 4; ++ks) {
        short8 a0 = *(const short8*)&Wb[(wv * 32 + i16) * 128 + ks * 32 + q * 8];
        short8 a1 = *(const short8*)&Wb[(wv * 32 + 16 + i16) * 128 + ks * 32 + q * 8];
#pragma unroll
        for (int pt = 0; pt < 8; ++pt) {
            short8 bb = *(const short8*)&Hb[(size_t)(pt * 16 + i16) * 128 + ks * 32 + q * 8];
            acc[0][pt] = __builtin_amdgcn_mfma_f32_16x16x32_bf16(a0, bb, acc[0][pt], 0, 0, 0);
            acc[1][pt] = __builtin_amdgcn_mfma_f32_16x16x32_bf16(a1, bb, acc[1][pt], 0, 0, 0);
        }
    }

    // epilogue: out = acc + b_out + x
    const float* xb = x + (size_t)b * (128 * NPOS) + p0;
    float* ob = out + (size_t)b * (128 * NPOS) + p0;
#pragma unroll
    for (int a = 0; a < 2; ++a) {
        int cb = wv * 32 + a * 16 + q * 4;
#pragma unroll
        for (int pt = 0; pt < 8; ++pt) {
            int p = pt * 16 + i16;
#pragma unroll
            for (int r = 0; r < 4; ++r) {
                int c = cb + r;
                ob[(size_t)c * NPOS + p] = acc[a][pt][r] + bo_s[c] + xb[(size_t)c * NPOS + p];
            }
        }
    }
}

extern "C" void kernel_launch(void* const* d_in, const int* in_sizes, int n_in,
                              void* d_out, int out_size, void* d_ws, size_t ws_size,
                              hipStream_t stream) {
    const float* x    = (const float*)d_in[0];
    const float* gn_w = (const float*)d_in[1];
    const float* gn_b = (const float*)d_in[2];
    const float* w_in = (const float*)d_in[3];
    const float* b_in = (const float*)d_in[4];
    const float* w_out= (const float*)d_in[5];
    const float* b_out= (const float*)d_in[6];
    float* out = (float*)d_out;

    // workspace layout (bytes):
    //   0      : stats   512 B   (128 f32)
    //   512    : Sg      65536 B (16384 f32, atomically accumulated)
    //   66048  : vA      4096 B  (1024 f32)
    //   70144  : Asb     262144 B (8*128*128 bf16: w_in*s per batch)
    //   332288 : weffb   262144 B (8*128*128 bf16)
    //   594432 : h1t     33554432 B (8*16384*128 bf16, [b][p][c])
    //   total ~34.2 MB
    char* ws = (char*)d_ws;
    float* stats          = (float*)(ws + 0);
    float* Sg             = (float*)(ws + 512);
    float* vA             = (float*)(ws + 66048);
    unsigned short* Asb   = (unsigned short*)(ws + 70144);
    unsigned short* weffb = (unsigned short*)(ws + 332288);
    unsigned short* h1t   = (unsigned short*)(ws + 594432);

    hipMemsetAsync(d_ws, 0, 66048, stream);
    k_stats<<<dim3(1024), dim3(256), 0, stream>>>(x, stats);
    k_prep<<<dim3(8), dim3(128), 0, stream>>>(stats, gn_w, gn_b, w_in, b_in, vA, Asb);
    k_gemm1_scores<<<dim3(1024), dim3(256), 0, stream>>>(x, Asb, vA, h1t, Sg);
    k_softmax_weff<<<dim3(64), dim3(256), 0, stream>>>(Sg, w_out, weffb);
    k_attn_out<<<dim3(1024), dim3(256), 0, stream>>>(x, weffb, h1t, b_out, out);
}